// Round 3
// baseline (243.801 us; speedup 1.0000x reference)
//
#include <hip/hip_runtime.h>
#include <hip/hip_bf16.h>

typedef __attribute__((ext_vector_type(4))) float f32x4;
typedef __attribute__((ext_vector_type(8))) short bf16x8;

// ---- workspace layout (bytes) ----
#define OFF_QS    0ull          // [131072][128] bf16  q softmaxed * 1/sqrt(32)
#define OFF_PCTX  33554432ull   // [256 blk][4 h][2 ns][32 d][32 e] f32 partials (8.39 MB)
#define OFF_PSE   41943040ull   // [256 blk][4 h][2 wm][32 d] f32 sum-exp partials (256 KB)
#define OFF_CTXG  42205184ull   // [32 b][4 h][32 d][32 e] bf16 normalized ctx (256 KB)
#define OFF_WQT   42467328ull   // [384][128] bf16 (W_qkv^T)
#define OFF_WOT   42565632ull   // [128][128] bf16 (W_out^T)
// total ~42.6 MB

static __device__ __forceinline__ unsigned short f2bf(float f) {
  unsigned int u = __builtin_bit_cast(unsigned int, f);
  return (unsigned short)((u + 0x7fffu + ((u >> 16) & 1u)) >> 16);  // RNE
}

// ---------------- k_prep: weights -> bf16, transposed for B-fragments ----------------
__global__ __launch_bounds__(256) void k_prep(const float* __restrict__ wqkv,
                                              const float* __restrict__ wout,
                                              unsigned short* __restrict__ wqT,
                                              unsigned short* __restrict__ woT) {
  int idx = blockIdx.x * 256 + threadIdx.x;   // grid covers exactly 65536
  if (idx < 49152) {                          // wqT[f][k] = wqkv[k][f]
    int f = idx >> 7, k = idx & 127;
    wqT[idx] = f2bf(wqkv[k * 384 + f]);
  } else {                                    // woT[c][k] = wout[k][c]
    int j = idx - 49152;
    int c = j >> 7, k = j & 127;
    woT[j] = f2bf(wout[k * 128 + c]);
  }
}

// ---------------- k_qkv_fused: x@Wqkv + q-softmax + fused EK^T*V chunk partials ----
// 256 persistent blocks (1/CU), 512 thr. Each block: 4 tiles of 128 rows (512 rows,
// all one batch). W staged once (96 KB LDS). A-region (32 KB) reused in epilogue for
// transposed ekT/vT head tiles; ctx partials accumulated in regs via MFMA.
__global__ __launch_bounds__(512, 2) void k_qkv_fused(const float* __restrict__ x,
                                                      const unsigned short* __restrict__ wqT,
                                                      unsigned short* __restrict__ qs,
                                                      float* __restrict__ pctx,
                                                      float* __restrict__ pse) {
  extern __shared__ char lds[];
  char* lds_w = lds;            // [384][128] bf16 swizzled, 98304 B
  char* lds_a = lds + 98304;    // 32768 B: A tile, then ekT[4][32][64] + vT[4][32][64]

  const int tid = threadIdx.x;
  const int beta = blockIdx.x;
  const int lane = tid & 63, g = lane >> 4, c = lane & 15;
  const int wave = tid >> 6, wm = wave >> 2, wf = wave & 3;
  const int h_task = wave & 3, ns_task = wave >> 2;   // ctx-mfma task: head, 32-n sub

  {  // stage W once (16B units, XOR bits 4-6 with row f)
    const int4* src = (const int4*)wqT;
    int4* dst = (int4*)lds_w;
#pragma unroll
    for (int i = 0; i < 12; i++) {
      int u = tid + i * 512;
      dst[u ^ ((u >> 4) & 7)] = src[u];
    }
  }

  // prefetch A(t=0): 128 B/thread f32
  f32x4 pre[8];
  {
    const f32x4* src = (const f32x4*)(x + (long)beta * 512 * 128);
#pragma unroll
    for (int i = 0; i < 8; i++) pre[i] = src[i * 512 + tid];
  }

  // persistent accumulators
  f32x4 cacc[2][2];                      // ctx partial C[32][32] for (h_task, ns_task)
#pragma unroll
  for (int dt = 0; dt < 2; dt++)
#pragma unroll
    for (int et = 0; et < 2; et++) cacc[dt][et] = (f32x4){0.f, 0.f, 0.f, 0.f};
  float seacc[3][2];                     // per-chunk sum-exp partials (ek chunks only)
#pragma unroll
  for (int i = 0; i < 3; i++) { seacc[i][0] = 0.f; seacc[i][1] = 0.f; }

  for (int t = 0; t < 4; t++) {
    const long rowbase = ((long)beta * 4 + t) * 128;
    __syncthreads();                     // A-region free (W staged / prev E4 done)

    {  // A-stage from prefetch regs: f32 -> bf16, swizzled
#pragma unroll
      for (int i = 0; i < 8; i++) {
        int u = i * 512 + tid;           // row = u>>5 (32 f32x4-units per row)
        f32x4 val = pre[i];
        ushort4 bq;
        bq.x = f2bf(val.x); bq.y = f2bf(val.y); bq.z = f2bf(val.z); bq.w = f2bf(val.w);
        int ba = (u * 8) ^ (((u >> 5) & 7) << 4);
        *(ushort4*)(lds_a + ba) = bq;
      }
    }
    if (t < 3) {                         // issue next tile's loads (in flight thru MFMA+epi)
      const f32x4* src = (const f32x4*)(x + (rowbase + 128) * 128);
#pragma unroll
      for (int i = 0; i < 8; i++) pre[i] = src[i * 512 + tid];
    }
    __syncthreads();                     // A ready

    // ---- main GEMM: wave (wm,wf) -> rows [64*wm,+64) x cols [96*wf,+96) ----
    f32x4 acc[4][6];
#pragma unroll
    for (int mt = 0; mt < 4; mt++)
#pragma unroll
      for (int ft = 0; ft < 6; ft++) acc[mt][ft] = (f32x4){0.f, 0.f, 0.f, 0.f};

#pragma unroll
    for (int kk = 0; kk < 4; kk++) {
      const int koff = (kk * 32 + g * 8) * 2;
      bf16x8 af[4], bfrag[6];
#pragma unroll
      for (int mt = 0; mt < 4; mt++) {
        int row = wm * 64 + mt * 16 + c;
        af[mt] = *(const bf16x8*)(lds_a + ((row * 256 + koff) ^ ((row & 7) << 4)));
      }
#pragma unroll
      for (int ft = 0; ft < 6; ft++) {
        int frow = wf * 96 + ft * 16 + c;
        bfrag[ft] = *(const bf16x8*)(lds_w + ((frow * 256 + koff) ^ ((frow & 7) << 4)));
      }
#pragma unroll
      for (int mt = 0; mt < 4; mt++)
#pragma unroll
        for (int ft = 0; ft < 6; ft++)
          acc[mt][ft] = __builtin_amdgcn_mfma_f32_16x16x32_bf16(af[mt], bfrag[ft], acc[mt][ft], 0, 0, 0);
    }
    __syncthreads();                     // A dead -> region reusable for ekT/vT

    // ---- epilogue: two half-passes over rows (wm halves) ----
    const float RS32 = 0.17677669529663687f;  // 1/sqrt(32)
#pragma unroll
    for (int half = 0; half < 2; half++) {
      // write phase: q stores (half 0 only, all waves) + this-half k/v LDS writes
#pragma unroll
      for (int ch = 0; ch < 3; ch++) {
        int gc = wf * 96 + ch * 32;
        int sec = gc >> 7;               // 0=q 1=k 2=v (wave-uniform)
        int sc = gc & 127;
        int h = (gc & 127) >> 5;         // head for sec 1/2
        if (sec == 0) {
          if (half == 0) {               // q softmax + direct store
#pragma unroll
            for (int mt = 0; mt < 4; mt++) {
              f32x4 a0 = acc[mt][2 * ch], a1 = acc[mt][2 * ch + 1];
              long row0 = rowbase + wm * 64 + mt * 16 + g * 4;
#pragma unroll
              for (int r = 0; r < 4; r++) {
                float e0 = __expf(a0[r]), e1 = __expf(a1[r]);
                float s = e0 + e1;
                s += __shfl_xor(s, 1); s += __shfl_xor(s, 2);
                s += __shfl_xor(s, 4); s += __shfl_xor(s, 8);
                float inv = RS32 / s;
                long base = (row0 + r) * 128 + sc + c;
                qs[base]      = f2bf(e0 * inv);
                qs[base + 16] = f2bf(e1 * inv);
              }
            }
          }
        } else if (wm == half) {         // k/v: transposed LDS write for this half
          char* tbase = lds_a + (sec == 1 ? 0 : 16384) + h * 4096;  // [32][64] bf16 swz
#pragma unroll
          for (int mt = 0; mt < 4; mt++) {
            f32x4 a0 = acc[mt][2 * ch], a1 = acc[mt][2 * ch + 1];
#pragma unroll
            for (int r = 0; r < 4; r++) {
              int nl = mt * 16 + g * 4 + r;          // n within half (0..63)
              float v0 = a0[r], v1 = a1[r];
              if (sec == 1) {
                v0 = __expf(v0); v1 = __expf(v1);
                seacc[ch][0] += v0; seacc[ch][1] += v1;
              }
              *(unsigned short*)(tbase + ((c * 128 + nl * 2) ^ ((c & 7) << 4))) = f2bf(v0);
              *(unsigned short*)(tbase + (((c + 16) * 128 + nl * 2) ^ ((c & 7) << 4))) = f2bf(v1);
            }
          }
        }
      }
      __syncthreads();                   // ekT/vT half ready

      // ctx-mfma phase: all 8 waves, task (h_task, ns_task), K=32 n of this half
      {
        const int noff = (ns_task * 32 + g * 8) * 2;
        bf16x8 afr[2], bfr[2];
#pragma unroll
        for (int dt = 0; dt < 2; dt++) {
          int row = dt * 16 + c;
          afr[dt] = *(const bf16x8*)(lds_a + h_task * 4096 + ((row * 128 + noff) ^ ((c & 7) << 4)));
        }
#pragma unroll
        for (int et = 0; et < 2; et++) {
          int row = et * 16 + c;
          bfr[et] = *(const bf16x8*)(lds_a + 16384 + h_task * 4096 + ((row * 128 + noff) ^ ((c & 7) << 4)));
        }
#pragma unroll
        for (int dt = 0; dt < 2; dt++)
#pragma unroll
          for (int et = 0; et < 2; et++)
            cacc[dt][et] = __builtin_amdgcn_mfma_f32_16x16x32_bf16(afr[dt], bfr[et], cacc[dt][et], 0, 0, 0);
      }
      __syncthreads();                   // half region free for next half / next A
    }
  }

  // ---- final: write ctx partials + sum-exp partials ----
  {
    const long pcbase = ((long)beta * 8 + h_task * 2 + ns_task) * 1024;
#pragma unroll
    for (int dt = 0; dt < 2; dt++)
#pragma unroll
      for (int et = 0; et < 2; et++)
#pragma unroll
        for (int r = 0; r < 4; r++)
          pctx[pcbase + (dt * 16 + g * 4 + r) * 32 + et * 16 + c] = cacc[dt][et][r];
  }
#pragma unroll
  for (int ch = 0; ch < 3; ch++) {
    int gc = wf * 96 + ch * 32;
    if ((gc >> 7) == 1) {                // ek chunk -> pse partial
      int h = (gc & 127) >> 5;
      float s0 = seacc[ch][0], s1 = seacc[ch][1];
      s0 += __shfl_xor(s0, 16); s0 += __shfl_xor(s0, 32);
      s1 += __shfl_xor(s1, 16); s1 += __shfl_xor(s1, 32);
      if (lane < 16) {
        pse[(beta * 8 + h * 2 + wm) * 32 + c]      = s0;
        pse[(beta * 8 + h * 2 + wm) * 32 + c + 16] = s1;
      }
    }
  }
}

// ---------------- k_ctxred: reduce 16 partials, normalize, emit ctx bf16 ----------------
__global__ __launch_bounds__(256) void k_ctxred(const float* __restrict__ pctx,
                                                const float* __restrict__ pse,
                                                unsigned short* __restrict__ ctxg) {
  int idx = blockIdx.x * 256 + threadIdx.x;   // 131072 = 32*4*32*32
  int de = idx & 1023, d = de >> 5;
  int bh = idx >> 10;                         // b*4 + h
  int b = bh >> 2, h = bh & 3;
  float s = 0.f, sume = 0.f;
#pragma unroll
  for (int i = 0; i < 8; i++) {
    int base = (b * 8 + i) * 8 + h * 2;
    s    += pctx[(long)(base + 0) * 1024 + de] + pctx[(long)(base + 1) * 1024 + de];
    sume += pse[(base + 0) * 32 + d] + pse[(base + 1) * 32 + d];
  }
  ctxg[idx] = f2bf(s / (sume * 4096.0f));     // softmax-normalize + v's 1/N
}

// ---------------- k_out: attn = q_s*ctx ; y = attn@Wout + b ; LayerNorm ----------------
__global__ __launch_bounds__(512, 2) void k_out(const unsigned short* __restrict__ qs,
                                                const unsigned short* __restrict__ ctxg,
                                                const unsigned short* __restrict__ woT,
                                                const float* __restrict__ bout,
                                                const float* __restrict__ lnsc,
                                                float* __restrict__ out) {
  extern __shared__ char lds[];
  char* lds_wo = lds;                                       // 32768 B, swizzled [c][k]
  char* lds_at = lds + 32768;                               // 32768 B, swizzled [row][col]
  unsigned short* lds_cx = (unsigned short*)(lds + 65536);  // [4][32 e][32 d] bf16, 8192 B
  float* lds_bias  = (float*)(lds + 73728);
  float* lds_scale = (float*)(lds + 74240);

  const int tid = threadIdx.x;
  const long rowbase = (long)blockIdx.x * 128;
  const int b = blockIdx.x >> 5;

  {  // stage Wout^T
    const int4* src = (const int4*)woT;
    int4* dst = (int4*)lds_wo;
#pragma unroll
    for (int i = 0; i < 4; i++) {
      int u = tid + i * 512;
      dst[u ^ ((u >> 4) & 7)] = src[u];
    }
  }
  {  // stage ctx [h][d][e] -> LDS transposed [h][e][d]
    const unsigned int* src = (const unsigned int*)(ctxg + (long)b * 4096);
#pragma unroll
    for (int i = 0; i < 4; i++) {
      int u = tid + i * 512;           // one uint = elems (j, j+1), j = 2u
      unsigned int w = src[u];
      int j = u * 2;
      int e = j & 31, d = (j >> 5) & 31, h = j >> 10;
      lds_cx[(h * 32 + e) * 32 + d]     = (unsigned short)(w & 0xffffu);
      lds_cx[(h * 32 + e + 1) * 32 + d] = (unsigned short)(w >> 16);
    }
  }
  if (tid < 128) { lds_bias[tid] = bout[tid]; lds_scale[tid] = lnsc[tid]; }
  __syncthreads();

  const int lane = tid & 63, g = lane >> 4, c = lane & 15;
  const int wave = tid >> 6;

  // GEMM1: attn[16 rows][128] ; A = q_s straight from global (L2), B = ctx from LDS
  f32x4 acc1[4][2];
#pragma unroll
  for (int h = 0; h < 4; h++) { acc1[h][0] = (f32x4){0.f,0.f,0.f,0.f}; acc1[h][1] = (f32x4){0.f,0.f,0.f,0.f}; }
  const unsigned short* qrow = qs + (rowbase + wave * 16 + c) * 128;
#pragma unroll
  for (int h = 0; h < 4; h++) {
    bf16x8 a = *(const bf16x8*)(qrow + h * 32 + g * 8);
#pragma unroll
    for (int et = 0; et < 2; et++) {
      bf16x8 bq = *(const bf16x8*)(lds_cx + (h * 32 + et * 16 + c) * 32 + g * 8);
      acc1[h][et] = __builtin_amdgcn_mfma_f32_16x16x32_bf16(a, bq, acc1[h][et], 0, 0, 0);
    }
  }
  {  // attn -> LDS (bf16, swizzled) for the A-fragment round trip
    int rowl = wave * 16 + g * 4;
#pragma unroll
    for (int h = 0; h < 4; h++)
#pragma unroll
      for (int et = 0; et < 2; et++) {
        int col = (2 * h + et) * 16 + c;
#pragma unroll
        for (int r = 0; r < 4; r++) {
          int row = rowl + r;
          int ba = (row * 256 + col * 2) ^ ((row & 7) << 4);
          *(unsigned short*)(lds_at + ba) = f2bf(acc1[h][et][r]);
        }
      }
  }
  __syncthreads();

  // GEMM2: y = attn @ Wout
  f32x4 acc2[8];
#pragma unroll
  for (int ct = 0; ct < 8; ct++) acc2[ct] = (f32x4){0.f,0.f,0.f,0.f};
#pragma unroll
  for (int kk = 0; kk < 4; kk++) {
    int koff = (kk * 32 + g * 8) * 2;
    int arow = wave * 16 + c;
    bf16x8 a = *(const bf16x8*)(lds_at + ((arow * 256 + koff) ^ ((arow & 7) << 4)));
#pragma unroll
    for (int ct = 0; ct < 8; ct++) {
      int wrow = ct * 16 + c;
      bf16x8 bw = *(const bf16x8*)(lds_wo + ((wrow * 256 + koff) ^ ((wrow & 7) << 4)));
      acc2[ct] = __builtin_amdgcn_mfma_f32_16x16x32_bf16(a, bw, acc2[ct], 0, 0, 0);
    }
  }

  // bias + LayerNorm (per-row over 128 channels, shuffle reduction)
  float biasv[8], scalev[8];
#pragma unroll
  for (int ct = 0; ct < 8; ct++) { biasv[ct] = lds_bias[ct * 16 + c]; scalev[ct] = lds_scale[ct * 16 + c]; }
#pragma unroll
  for (int ct = 0; ct < 8; ct++)
#pragma unroll
    for (int r = 0; r < 4; r++)
      acc2[ct][r] += biasv[ct];

#pragma unroll
  for (int r = 0; r < 4; r++) {
    float s = 0.f, ss = 0.f;
#pragma unroll
    for (int ct = 0; ct < 8; ct++) { float v = acc2[ct][r]; s += v; ss += v * v; }
    s  += __shfl_xor(s, 1);  s  += __shfl_xor(s, 2);  s  += __shfl_xor(s, 4);  s  += __shfl_xor(s, 8);
    ss += __shfl_xor(ss, 1); ss += __shfl_xor(ss, 2); ss += __shfl_xor(ss, 4); ss += __shfl_xor(ss, 8);
    float mu = s * 0.0078125f;
    float var = ss * 0.0078125f - mu * mu;
    float rstd = rsqrtf(var + 1e-5f);
    long row = rowbase + wave * 16 + g * 4 + r;
#pragma unroll
    for (int ct = 0; ct < 8; ct++)
      out[row * 128 + ct * 16 + c] = (acc2[ct][r] - mu) * rstd * scalev[ct];
  }
}

// ---------------- host ----------------
extern "C" void kernel_launch(void* const* d_in, const int* in_sizes, int n_in,
                              void* d_out, int out_size, void* d_ws, size_t ws_size,
                              hipStream_t stream) {
  (void)in_sizes; (void)n_in; (void)out_size; (void)ws_size;
  const float* x     = (const float*)d_in[0];
  const float* wqkv  = (const float*)d_in[1];
  const float* wout  = (const float*)d_in[2];
  const float* bo    = (const float*)d_in[3];
  const float* lnsc  = (const float*)d_in[4];
  float* out = (float*)d_out;

  char* ws = (char*)d_ws;
  unsigned short* qs   = (unsigned short*)(ws + OFF_QS);
  float*          pctx = (float*)(ws + OFF_PCTX);
  float*          pse  = (float*)(ws + OFF_PSE);
  unsigned short* ctxg = (unsigned short*)(ws + OFF_CTXG);
  unsigned short* wqT  = (unsigned short*)(ws + OFF_WQT);
  unsigned short* woT  = (unsigned short*)(ws + OFF_WOT);

  k_prep<<<dim3(256), dim3(256), 0, stream>>>(wqkv, wout, wqT, woT);
  k_qkv_fused<<<dim3(256), dim3(512), 131072, stream>>>(x, wqT, qs, pctx, pse);
  k_ctxred<<<dim3(512), dim3(256), 0, stream>>>(pctx, pse, ctxg);
  k_out<<<dim3(1024), dim3(512), 74752, stream>>>(qs, ctxg, woT, bo, lnsc, out);
}

// Round 7
// 233.224 us; speedup vs baseline: 1.0454x; 1.0454x over previous
//
#include <hip/hip_runtime.h>
#include <hip/hip_bf16.h>

typedef __attribute__((ext_vector_type(4))) float f32x4;
typedef __attribute__((ext_vector_type(8))) short bf16x8;

// ---- workspace layout (bytes) ----
#define OFF_QS    0ull                     // [131072][128] bf16  q softmaxed * 1/sqrt(32)
#define OFF_EK    33554432ull              // [131072][128] bf16  exp(k)
#define OFF_VV    67108864ull              // [131072][128] bf16  v (raw)
#define OFF_PCTX  100663296ull             // [16][128][32][32] f32 chunk partials
#define OFF_PSE   109051904ull             // [16][128][32] f32 chunk sum-exp
#define OFF_CTXG  109314048ull             // [32][4][32][32] bf16 normalized ctx
#define OFF_WQT   109576192ull             // [384][128] bf16 (W_qkv^T)
#define OFF_WOT   109674496ull             // [128][128] bf16 (W_out^T)
// total 109707264 bytes (~104.6 MiB)

static __device__ __forceinline__ unsigned short f2bf(float f) {
  unsigned int u = __builtin_bit_cast(unsigned int, f);
  return (unsigned short)((u + 0x7fffu + ((u >> 16) & 1u)) >> 16);  // RNE
}

static __device__ __forceinline__ void unpack8(uint4 u, float* p) {
  p[0] = __builtin_bit_cast(float, u.x << 16);
  p[1] = __builtin_bit_cast(float, u.x & 0xffff0000u);
  p[2] = __builtin_bit_cast(float, u.y << 16);
  p[3] = __builtin_bit_cast(float, u.y & 0xffff0000u);
  p[4] = __builtin_bit_cast(float, u.z << 16);
  p[5] = __builtin_bit_cast(float, u.z & 0xffff0000u);
  p[6] = __builtin_bit_cast(float, u.w << 16);
  p[7] = __builtin_bit_cast(float, u.w & 0xffff0000u);
}

// ---------------- k_prep: weights -> bf16, transposed for B-fragments ----------------
__global__ __launch_bounds__(256) void k_prep(const float* __restrict__ wqkv,
                                              const float* __restrict__ wout,
                                              unsigned short* __restrict__ wqT,
                                              unsigned short* __restrict__ woT) {
  int idx = blockIdx.x * 256 + threadIdx.x;   // grid covers exactly 65536
  if (idx < 49152) {                          // wqT[f][k] = wqkv[k][f]
    int f = idx >> 7, k = idx & 127;
    wqT[idx] = f2bf(wqkv[k * 384 + f]);
  } else {                                    // woT[c][k] = wout[k][c]
    int j = idx - 49152;
    int c = j >> 7, k = j & 127;
    woT[j] = f2bf(wout[k * 128 + c]);
  }
}

// ---------------- k_qkv: x@Wqkv + q-softmax + exp(k); 128 rows/block ----------------
// Epilogue stores re-laid through LDS (reusing the dead W region) so every global
// store instr writes 1KB contiguous (store-coalescing was the round-2 bottleneck).
__global__ __launch_bounds__(512, 2) void k_qkv(const float* __restrict__ x,
                                                const unsigned short* __restrict__ wqT,
                                                unsigned short* __restrict__ qs,
                                                unsigned short* __restrict__ ek,
                                                unsigned short* __restrict__ vv) {
  extern __shared__ char lds[];
  char* lds_w = lds;            // [384][128] bf16, XOR-swizzled, 98304 B; flush buf later
  char* lds_a = lds + 98304;    // [128][128] bf16, XOR-swizzled, 32768 B

  const int tid = threadIdx.x;
  const long rowbase = (long)blockIdx.x * 128;

  {  // stage W (bf16, 16B units); swizzle XOR bits 4-6 with row f (G4)
    const int4* src = (const int4*)wqT;
    int4* dst = (int4*)lds_w;
#pragma unroll
    for (int i = 0; i < 12; i++) {
      int u = tid + i * 512;                 // row f = u>>4 (16 units/row)
      dst[u ^ ((u >> 4) & 7)] = src[u];
    }
  }
  {  // stage A: f32 -> bf16 (8B units); row = u>>5
    const f32x4* src = (const f32x4*)(x + rowbase * 128);
#pragma unroll
    for (int i = 0; i < 8; i++) {
      int u = tid + i * 512;
      f32x4 val = src[u];
      ushort4 bq;
      bq.x = f2bf(val.x); bq.y = f2bf(val.y); bq.z = f2bf(val.z); bq.w = f2bf(val.w);
      int ba = (u * 8) ^ (((u >> 5) & 7) << 4);
      *(ushort4*)(lds_a + ba) = bq;
    }
  }
  __syncthreads();

  const int lane = tid & 63;
  const int g = lane >> 4, c = lane & 15;
  const int wave = tid >> 6;
  const int wm = wave >> 2, wf = wave & 3;   // rows [64*wm,+64) x cols [96*wf,+96)

  f32x4 acc[4][6];
#pragma unroll
  for (int mt = 0; mt < 4; mt++)
#pragma unroll
    for (int ft = 0; ft < 6; ft++)
      acc[mt][ft] = (f32x4){0.f, 0.f, 0.f, 0.f};

#pragma unroll
  for (int kk = 0; kk < 4; kk++) {
    const int koff = (kk * 32 + g * 8) * 2;
    bf16x8 af[4], bfrag[6];
#pragma unroll
    for (int mt = 0; mt < 4; mt++) {
      int row = wm * 64 + mt * 16 + c;
      af[mt] = *(const bf16x8*)(lds_a + ((row * 256 + koff) ^ ((row & 7) << 4)));
    }
#pragma unroll
    for (int ft = 0; ft < 6; ft++) {
      int frow = wf * 96 + ft * 16 + c;
      bfrag[ft] = *(const bf16x8*)(lds_w + ((frow * 256 + koff) ^ ((frow & 7) << 4)));
    }
#pragma unroll
    for (int mt = 0; mt < 4; mt++)
#pragma unroll
      for (int ft = 0; ft < 6; ft++)
        acc[mt][ft] = __builtin_amdgcn_mfma_f32_16x16x32_bf16(af[mt], bfrag[ft], acc[mt][ft], 0, 0, 0);
  }
  __syncthreads();                           // W+A dead -> lds becomes flush buffer

  // epilogue: compute q-softmax / exp(k) / v and write bf16 into flush buffer
  // flush layout: [sec][128 rows][128 cols] bf16, row-swizzled (XOR bits 4-6)
  const float RS32 = 0.17677669529663687f;   // 1/sqrt(32)
#pragma unroll
  for (int ch = 0; ch < 3; ch++) {
    int gc = wf * 96 + ch * 32;
    int sec = gc >> 7;                       // 0=q 1=k 2=v (wave-uniform)
    int sc = gc & 127;
    char* fb = lds + sec * 32768;
#pragma unroll
    for (int mt = 0; mt < 4; mt++) {
      f32x4 a0 = acc[mt][2 * ch];
      f32x4 a1 = acc[mt][2 * ch + 1];
      int row0 = wm * 64 + mt * 16 + g * 4;  // local row
      if (sec == 0) {                        // softmax over the head's 32 dims
#pragma unroll
        for (int r = 0; r < 4; r++) {
          float e0 = __expf(a0[r]), e1 = __expf(a1[r]);
          float s = e0 + e1;
          s += __shfl_xor(s, 1); s += __shfl_xor(s, 2);
          s += __shfl_xor(s, 4); s += __shfl_xor(s, 8);
          float inv = RS32 / s;
          int row = row0 + r;
          *(unsigned short*)(fb + ((row * 256 + (sc + c) * 2)      ^ ((row & 7) << 4))) = f2bf(e0 * inv);
          *(unsigned short*)(fb + ((row * 256 + (sc + c + 16) * 2) ^ ((row & 7) << 4))) = f2bf(e1 * inv);
        }
      } else if (sec == 1) {                 // exp(k) (no max-sub: k ~ N(0,1))
#pragma unroll
        for (int r = 0; r < 4; r++) {
          int row = row0 + r;
          *(unsigned short*)(fb + ((row * 256 + (sc + c) * 2)      ^ ((row & 7) << 4))) = f2bf(__expf(a0[r]));
          *(unsigned short*)(fb + ((row * 256 + (sc + c + 16) * 2) ^ ((row & 7) << 4))) = f2bf(__expf(a1[r]));
        }
      } else {                               // raw v (1/N folded into ctx normalize)
#pragma unroll
        for (int r = 0; r < 4; r++) {
          int row = row0 + r;
          *(unsigned short*)(fb + ((row * 256 + (sc + c) * 2)      ^ ((row & 7) << 4))) = f2bf(a0[r]);
          *(unsigned short*)(fb + ((row * 256 + (sc + c + 16) * 2) ^ ((row & 7) << 4))) = f2bf(a1[r]);
        }
      }
    }
  }
  __syncthreads();

  // cooperative streaming flush: 6144 int4 units, 1KB contiguous per wave-instr
  {
    const long off16 = (long)blockIdx.x * 2048;   // rowbase * 256B / 16
#pragma unroll
    for (int i = 0; i < 12; i++) {
      int u = tid + i * 512;
      int sec = u >> 11;                     // wave-uniform per i
      int w = u & 2047, row = w >> 4;
      int4 val = *(const int4*)(lds + sec * 32768 + ((w * 16) ^ ((row & 7) << 4)));
      int4* dst = (sec == 0) ? (int4*)qs : (sec == 1 ? (int4*)ek : (int4*)vv);
      dst[off16 + w] = val;
    }
  }
}

// ---------------- k_ctx: chunk partials of EK^T·V and sum-exp ----------------
// grid (16 chunks, 32 batches) x 256 thr; wave = head; lane owns 4x4 (d,e) tile
__global__ __launch_bounds__(256) void k_ctx(const unsigned short* __restrict__ ek,
                                             const unsigned short* __restrict__ vv,
                                             float* __restrict__ pctx,
                                             float* __restrict__ pse) {
  extern __shared__ char lds[];
  float* ekc = (float*)lds;            // [4][64][32]
  float* vcc = (float*)(lds + 32768);  // [4][64][32]

  const int tid = threadIdx.x;
  const int chunk = blockIdx.x, b = blockIdx.y;
  const long row0 = (long)b * 4096 + chunk * 256;
  const int wave = tid >> 6, lane = tid & 63;
  const int d0 = (lane >> 3) * 4, e0 = (lane & 7) * 4;
  const int nn = tid >> 2, part = tid & 3;

  f32x4 acc0 = {0.f,0.f,0.f,0.f}, acc1 = {0.f,0.f,0.f,0.f};
  f32x4 acc2 = {0.f,0.f,0.f,0.f}, acc3 = {0.f,0.f,0.f,0.f};
  f32x4 se   = {0.f,0.f,0.f,0.f};

  for (int s = 0; s < 4; s++) {
    long r = row0 + s * 64 + nn;
#pragma unroll
    for (int h = 0; h < 4; h++) {          // stage all 4 head-slices, f32
      uint4 ue = *(const uint4*)(ek + r * 128 + h * 32 + part * 8);
      uint4 uv = *(const uint4*)(vv + r * 128 + h * 32 + part * 8);
      unpack8(ue, &ekc[(h * 64 + nn) * 32 + part * 8]);
      unpack8(uv, &vcc[(h * 64 + nn) * 32 + part * 8]);
    }
    __syncthreads();
    const float* eb = &ekc[(wave * 64) * 32];
    const float* vb = &vcc[(wave * 64) * 32];
#pragma unroll 4
    for (int n = 0; n < 64; n++) {
      f32x4 ev  = *(const f32x4*)(eb + n * 32 + d0);
      f32x4 v4  = *(const f32x4*)(vb + n * 32 + e0);
      acc0 += ev.x * v4;
      acc1 += ev.y * v4;
      acc2 += ev.z * v4;
      acc3 += ev.w * v4;
      se += ev;
    }
    __syncthreads();
  }
  const long pb = ((long)chunk * 128 + b * 4 + wave) * 1024;
  *(f32x4*)&pctx[pb + (d0 + 0) * 32 + e0] = acc0;
  *(f32x4*)&pctx[pb + (d0 + 1) * 32 + e0] = acc1;
  *(f32x4*)&pctx[pb + (d0 + 2) * 32 + e0] = acc2;
  *(f32x4*)&pctx[pb + (d0 + 3) * 32 + e0] = acc3;
  if ((lane & 7) == 0)
    *(f32x4*)&pse[((long)chunk * 128 + b * 4 + wave) * 32 + d0] = se;
}

// ---------------- k_ctxred: reduce 16 chunks, normalize, emit ctx bf16 ----------------
__global__ __launch_bounds__(256) void k_ctxred(const float* __restrict__ pctx,
                                                const float* __restrict__ pse,
                                                unsigned short* __restrict__ ctxg) {
  int idx = blockIdx.x * 256 + threadIdx.x;   // 131072 = 32*4*32*32
  int de = idx & 1023, d = de >> 5, bh = idx >> 10;
  float s = 0.f, sume = 0.f;
#pragma unroll
  for (int ch = 0; ch < 16; ch++) {
    s    += pctx[(ch * 128 + bh) * 1024 + de];
    sume += pse[(ch * 128 + bh) * 32 + d];
  }
  ctxg[idx] = f2bf(s / (sume * 4096.0f));     // softmax-normalize + v's 1/N
}

// ---------------- k_out: attn = q_s*ctx ; y = attn@Wout + b ; LayerNorm ----------------
// Output stores re-laid through LDS (reusing dead lds_at) -> contiguous dwordx4 streams.
__global__ __launch_bounds__(512, 2) void k_out(const unsigned short* __restrict__ qs,
                                                const unsigned short* __restrict__ ctxg,
                                                const unsigned short* __restrict__ woT,
                                                const float* __restrict__ bout,
                                                const float* __restrict__ lnsc,
                                                float* __restrict__ out) {
  extern __shared__ char lds[];
  char* lds_wo = lds;                                       // 32768 B, swizzled [c][k]
  char* lds_at = lds + 32768;                               // 32768 B, swizzled [row][col]; f32 flush later
  unsigned short* lds_cx = (unsigned short*)(lds + 65536);  // [4][32 e][32 d] bf16, 8192 B
  float* lds_bias  = (float*)(lds + 73728);
  float* lds_scale = (float*)(lds + 74240);

  const int tid = threadIdx.x;
  const long rowbase = (long)blockIdx.x * 128;
  const int b = blockIdx.x >> 5;

  {  // stage Wout^T
    const int4* src = (const int4*)woT;
    int4* dst = (int4*)lds_wo;
#pragma unroll
    for (int i = 0; i < 4; i++) {
      int u = tid + i * 512;
      dst[u ^ ((u >> 4) & 7)] = src[u];
    }
  }
  {  // stage ctx [h][d][e] -> LDS transposed [h][e][d]
    const unsigned int* src = (const unsigned int*)(ctxg + (long)b * 4096);
#pragma unroll
    for (int i = 0; i < 4; i++) {
      int u = tid + i * 512;           // one uint = elems (j, j+1), j = 2u
      unsigned int w = src[u];
      int j = u * 2;
      int e = j & 31, d = (j >> 5) & 31, h = j >> 10;
      lds_cx[(h * 32 + e) * 32 + d]     = (unsigned short)(w & 0xffffu);
      lds_cx[(h * 32 + e + 1) * 32 + d] = (unsigned short)(w >> 16);
    }
  }
  if (tid < 128) { lds_bias[tid] = bout[tid]; lds_scale[tid] = lnsc[tid]; }
  __syncthreads();

  const int lane = tid & 63, g = lane >> 4, c = lane & 15;
  const int wave = tid >> 6;

  // GEMM1: attn[16 rows][128] ; A = q_s straight from global (L2), B = ctx from LDS
  f32x4 acc1[4][2];
#pragma unroll
  for (int h = 0; h < 4; h++) { acc1[h][0] = (f32x4){0.f,0.f,0.f,0.f}; acc1[h][1] = (f32x4){0.f,0.f,0.f,0.f}; }
  const unsigned short* qrow = qs + (rowbase + wave * 16 + c) * 128;
#pragma unroll
  for (int h = 0; h < 4; h++) {
    bf16x8 a = *(const bf16x8*)(qrow + h * 32 + g * 8);
#pragma unroll
    for (int et = 0; et < 2; et++) {
      bf16x8 bq = *(const bf16x8*)(lds_cx + (h * 32 + et * 16 + c) * 32 + g * 8);
      acc1[h][et] = __builtin_amdgcn_mfma_f32_16x16x32_bf16(a, bq, acc1[h][et], 0, 0, 0);
    }
  }
  {  // attn -> LDS (bf16, swizzled) for the A-fragment round trip
    int rowl = wave * 16 + g * 4;
#pragma unroll
    for (int h = 0; h < 4; h++)
#pragma unroll
      for (int et = 0; et < 2; et++) {
        int col = (2 * h + et) * 16 + c;
#pragma unroll
        for (int r = 0; r < 4; r++) {
          int row = rowl + r;
          int ba = (row * 256 + col * 2) ^ ((row & 7) << 4);
          *(unsigned short*)(lds_at + ba) = f2bf(acc1[h][et][r]);
        }
      }
  }
  __syncthreads();

  // GEMM2: y = attn @ Wout
  f32x4 acc2[8];
#pragma unroll
  for (int ct = 0; ct < 8; ct++) acc2[ct] = (f32x4){0.f,0.f,0.f,0.f};
#pragma unroll
  for (int kk = 0; kk < 4; kk++) {
    int koff = (kk * 32 + g * 8) * 2;
    int arow = wave * 16 + c;
    bf16x8 a = *(const bf16x8*)(lds_at + ((arow * 256 + koff) ^ ((arow & 7) << 4)));
#pragma unroll
    for (int ct = 0; ct < 8; ct++) {
      int wrow = ct * 16 + c;
      bf16x8 bw = *(const bf16x8*)(lds_wo + ((wrow * 256 + koff) ^ ((wrow & 7) << 4)));
      acc2[ct] = __builtin_amdgcn_mfma_f32_16x16x32_bf16(a, bw, acc2[ct], 0, 0, 0);
    }
  }

  // bias + LayerNorm (per-row over 128 channels, shuffle reduction) -> keep in regs
  float biasv[8], scalev[8];
#pragma unroll
  for (int ct = 0; ct < 8; ct++) { biasv[ct] = lds_bias[ct * 16 + c]; scalev[ct] = lds_scale[ct * 16 + c]; }
#pragma unroll
  for (int ct = 0; ct < 8; ct++)
#pragma unroll
    for (int r = 0; r < 4; r++)
      acc2[ct][r] += biasv[ct];

#pragma unroll
  for (int r = 0; r < 4; r++) {
    float s = 0.f, ss = 0.f;
#pragma unroll
    for (int ct = 0; ct < 8; ct++) { float v = acc2[ct][r]; s += v; ss += v * v; }
    s  += __shfl_xor(s, 1);  s  += __shfl_xor(s, 2);  s  += __shfl_xor(s, 4);  s  += __shfl_xor(s, 8);
    ss += __shfl_xor(ss, 1); ss += __shfl_xor(ss, 2); ss += __shfl_xor(ss, 4); ss += __shfl_xor(ss, 8);
    float mu = s * 0.0078125f;
    float var = ss * 0.0078125f - mu * mu;
    float rstd = rsqrtf(var + 1e-5f);
#pragma unroll
    for (int ct = 0; ct < 8; ct++)
      acc2[ct][r] = (acc2[ct][r] - mu) * rstd * scalev[ct];
  }

  // coalesced store via lds_at (f32), two 64-row half-passes of 32KB each
#pragma unroll
  for (int half = 0; half < 2; half++) {
    __syncthreads();                     // lds_at free (after GEMM2 / previous flush)
    if ((wave >> 2) == half) {
      int rl0 = (wave & 3) * 16 + g * 4; // local row within half (0..63)
#pragma unroll
      for (int ct = 0; ct < 8; ct++)
#pragma unroll
        for (int r = 0; r < 4; r++) {
          int rl = rl0 + r;
          *(float*)(lds_at + ((rl * 512 + (ct * 16 + c) * 4) ^ ((rl & 7) << 4))) = acc2[ct][r];
        }
    }
    __syncthreads();
    {
      const long base = (rowbase + half * 64) * 32;   // int4 units (32 per 128-f32 row)
#pragma unroll
      for (int i = 0; i < 4; i++) {
        int u = tid + i * 512;
        int row = u >> 5;
        int4 v = *(const int4*)(lds_at + ((u * 16) ^ ((row & 7) << 4)));
        ((int4*)out)[base + u] = v;
      }
    }
  }
}

// ---------------- host ----------------
extern "C" void kernel_launch(void* const* d_in, const int* in_sizes, int n_in,
                              void* d_out, int out_size, void* d_ws, size_t ws_size,
                              hipStream_t stream) {
  (void)in_sizes; (void)n_in; (void)out_size; (void)ws_size;
  const float* x     = (const float*)d_in[0];
  const float* wqkv  = (const float*)d_in[1];
  const float* wout  = (const float*)d_in[2];
  const float* bo    = (const float*)d_in[3];
  const float* lnsc  = (const float*)d_in[4];
  float* out = (float*)d_out;

  char* ws = (char*)d_ws;
  unsigned short* qs   = (unsigned short*)(ws + OFF_QS);
  unsigned short* ek   = (unsigned short*)(ws + OFF_EK);
  unsigned short* vv   = (unsigned short*)(ws + OFF_VV);
  float*          pctx = (float*)(ws + OFF_PCTX);
  float*          pse  = (float*)(ws + OFF_PSE);
  unsigned short* ctxg = (unsigned short*)(ws + OFF_CTXG);
  unsigned short* wqT  = (unsigned short*)(ws + OFF_WQT);
  unsigned short* woT  = (unsigned short*)(ws + OFF_WOT);

  k_prep<<<dim3(256), dim3(256), 0, stream>>>(wqkv, wout, wqT, woT);
  k_qkv<<<dim3(1024), dim3(512), 131072, stream>>>(x, wqT, qs, ek, vv);
  k_ctx<<<dim3(16, 32), dim3(256), 65536, stream>>>(ek, vv, pctx, pse);
  k_ctxred<<<dim3(512), dim3(256), 0, stream>>>(pctx, pse, ctxg);
  k_out<<<dim3(1024), dim3(512), 74752, stream>>>(qs, ctxg, woT, bo, lnsc, out);
}

// Round 8
// 195.159 us; speedup vs baseline: 1.2492x; 1.1950x over previous
//
#include <hip/hip_runtime.h>
#include <hip/hip_bf16.h>

typedef __attribute__((ext_vector_type(4))) float f32x4;
typedef __attribute__((ext_vector_type(8))) short bf16x8;
typedef __attribute__((ext_vector_type(8))) unsigned short u16x8;

// ---- workspace layout (bytes) ----
#define OFF_QS    0ull                     // [131072][128] bf16  q softmaxed * 1/sqrt(32)
#define OFF_EK    33554432ull              // [4 h][131072 n][32 d] bf16  exp(k), head-split
#define OFF_VV    67108864ull              // [4 h][131072 n][32 e] bf16  v, head-split
#define OFF_PCTX  100663296ull             // [16][128][32][32] f32 chunk partials
#define OFF_PSE   109051904ull             // [16][128][32] f32 chunk sum-exp
#define OFF_CTXG  109314048ull             // [32][4][32][32] bf16 normalized ctx
#define OFF_WQT   109576192ull             // [384][128] bf16 (W_qkv^T)
#define OFF_WOT   109674496ull             // [128][128] bf16 (W_out^T)
// total 109707264 bytes (~104.6 MiB)

static __device__ __forceinline__ unsigned short f2bf(float f) {
  unsigned int u = __builtin_bit_cast(unsigned int, f);
  return (unsigned short)((u + 0x7fffu + ((u >> 16) & 1u)) >> 16);  // RNE
}
static __device__ __forceinline__ float bf2f(unsigned short v) {
  return __builtin_bit_cast(float, (unsigned int)v << 16);
}

// ---------------- k_prep: weights -> bf16, transposed for B-fragments ----------------
__global__ __launch_bounds__(256) void k_prep(const float* __restrict__ wqkv,
                                              const float* __restrict__ wout,
                                              unsigned short* __restrict__ wqT,
                                              unsigned short* __restrict__ woT) {
  int idx = blockIdx.x * 256 + threadIdx.x;   // grid covers exactly 65536
  if (idx < 49152) {                          // wqT[f][k] = wqkv[k][f]
    int f = idx >> 7, k = idx & 127;
    wqT[idx] = f2bf(wqkv[k * 384 + f]);
  } else {                                    // woT[c][k] = wout[k][c]
    int j = idx - 49152;
    int c = j >> 7, k = j & 127;
    woT[j] = f2bf(wout[k * 128 + c]);
  }
}

// ---------------- k_qkv: one SECTION (q|k|v) of x@Wqkv per block ----------------
// grid (1024 tiles, 3 sections). LDS 64KB -> 2 blocks/CU (occupancy was the round-7
// bottleneck: 20% occ, nothing saturated). Epilogue flushed via LDS, coalesced.
__global__ __launch_bounds__(512, 4) void k_qkv(const float* __restrict__ x,
                                                const unsigned short* __restrict__ wqT,
                                                unsigned short* __restrict__ qs,
                                                unsigned short* __restrict__ ekh,
                                                unsigned short* __restrict__ vvh) {
  extern __shared__ char lds[];
  char* lds_w = lds;            // [128 f][128 k] bf16 swizzled, 32768 B (flush buf later)
  char* lds_a = lds + 32768;    // [128 n][128 k] bf16 swizzled, 32768 B

  const int tid = threadIdx.x;
  const int tile = blockIdx.x;                 // 0..1023
  const int sec = blockIdx.y;                  // 0=q 1=k 2=v
  const long rowbase = (long)tile * 128;

  {  // stage W slice rows [sec*128, +128): 2048 int4
    const int4* src = (const int4*)wqT + sec * 2048;
#pragma unroll
    for (int i = 0; i < 4; i++) {
      int u = tid + i * 512;                   // row f = u>>4
      ((int4*)lds_w)[u ^ ((u >> 4) & 7)] = src[u];
    }
  }
  {  // stage A: f32 -> bf16; row = u>>5
    const f32x4* src = (const f32x4*)(x + rowbase * 128);
#pragma unroll
    for (int i = 0; i < 8; i++) {
      int u = tid + i * 512;
      f32x4 val = src[u];
      ushort4 bq;
      bq.x = f2bf(val.x); bq.y = f2bf(val.y); bq.z = f2bf(val.z); bq.w = f2bf(val.w);
      int ba = (u * 8) ^ (((u >> 5) & 7) << 4);
      *(ushort4*)(lds_a + ba) = bq;
    }
  }
  __syncthreads();

  const int lane = tid & 63, g = lane >> 4, c = lane & 15;
  const int wave = tid >> 6;
  const int wm = wave >> 2, wf = wave & 3;     // rows [64*wm,+64) x cols [32*wf,+32)

  f32x4 acc[4][2];
#pragma unroll
  for (int mt = 0; mt < 4; mt++) { acc[mt][0] = (f32x4){0.f,0.f,0.f,0.f}; acc[mt][1] = (f32x4){0.f,0.f,0.f,0.f}; }

#pragma unroll
  for (int kk = 0; kk < 4; kk++) {
    const int koff = (kk * 32 + g * 8) * 2;
    bf16x8 af[4], bfrag[2];
#pragma unroll
    for (int mt = 0; mt < 4; mt++) {
      int row = wm * 64 + mt * 16 + c;
      af[mt] = *(const bf16x8*)(lds_a + ((row * 256 + koff) ^ ((row & 7) << 4)));
    }
#pragma unroll
    for (int ft = 0; ft < 2; ft++) {
      int frow = wf * 32 + ft * 16 + c;
      bfrag[ft] = *(const bf16x8*)(lds_w + ((frow * 256 + koff) ^ ((frow & 7) << 4)));
    }
#pragma unroll
    for (int mt = 0; mt < 4; mt++)
#pragma unroll
      for (int ft = 0; ft < 2; ft++)
        acc[mt][ft] = __builtin_amdgcn_mfma_f32_16x16x32_bf16(af[mt], bfrag[ft], acc[mt][ft], 0, 0, 0);
  }
  __syncthreads();                             // W+A dead -> lds[0..32768) = flush buffer

  // epilogue into flush buffer [128 rows][128 cols] bf16, row-swizzled
  const float RS32 = 0.17677669529663687f;     // 1/sqrt(32)
  const int sc = wf * 32;
#pragma unroll
  for (int mt = 0; mt < 4; mt++) {
    f32x4 a0 = acc[mt][0], a1 = acc[mt][1];
    int row0 = wm * 64 + mt * 16 + g * 4;
    if (sec == 0) {                            // q: softmax over the head's 32 dims (head=wf)
#pragma unroll
      for (int r = 0; r < 4; r++) {
        float e0 = __expf(a0[r]), e1 = __expf(a1[r]);
        float s = e0 + e1;
        s += __shfl_xor(s, 1); s += __shfl_xor(s, 2);
        s += __shfl_xor(s, 4); s += __shfl_xor(s, 8);
        float inv = RS32 / s;
        int row = row0 + r;
        *(unsigned short*)(lds + ((row * 256 + (sc + c) * 2)      ^ ((row & 7) << 4))) = f2bf(e0 * inv);
        *(unsigned short*)(lds + ((row * 256 + (sc + c + 16) * 2) ^ ((row & 7) << 4))) = f2bf(e1 * inv);
      }
    } else if (sec == 1) {                     // exp(k) (no max-sub: k ~ N(0,1))
#pragma unroll
      for (int r = 0; r < 4; r++) {
        int row = row0 + r;
        *(unsigned short*)(lds + ((row * 256 + (sc + c) * 2)      ^ ((row & 7) << 4))) = f2bf(__expf(a0[r]));
        *(unsigned short*)(lds + ((row * 256 + (sc + c + 16) * 2) ^ ((row & 7) << 4))) = f2bf(__expf(a1[r]));
      }
    } else {                                   // raw v
#pragma unroll
      for (int r = 0; r < 4; r++) {
        int row = row0 + r;
        *(unsigned short*)(lds + ((row * 256 + (sc + c) * 2)      ^ ((row & 7) << 4))) = f2bf(a0[r]);
        *(unsigned short*)(lds + ((row * 256 + (sc + c + 16) * 2) ^ ((row & 7) << 4))) = f2bf(a1[r]);
      }
    }
  }
  __syncthreads();

  // cooperative flush: 2048 int4
  if (sec == 0) {                              // qs: [n][128] layout
    const long off16 = (long)tile * 2048;
#pragma unroll
    for (int i = 0; i < 4; i++) {
      int u = tid + i * 512;
      int row = u >> 4;
      int4 v = *(const int4*)(lds + ((u * 16) ^ ((row & 7) << 4)));
      ((int4*)qs)[off16 + u] = v;
    }
  } else {                                     // ek/vv: head-split [h][n][32]
    unsigned short* dsth = (sec == 1) ? ekh : vvh;
#pragma unroll
    for (int i = 0; i < 4; i++) {
      int u = tid + i * 512;
      int row = u >> 4, col16 = u & 15;
      int h = col16 >> 2, q4 = col16 & 3;
      int4 v = *(const int4*)(lds + ((u * 16) ^ ((row & 7) << 4)));
      long di = ((long)h * 131072 + tile * 128 + row) * 4 + q4;   // int4 units
      ((int4*)dsth)[di] = v;
    }
  }
}

// ---------------- k_ctx: EK^T*V via MFMA; 16 partials per (b,h) ----------------
// grid (16 = quarter*4+h, 32 b) x 256 thr (4 waves). Per block: n in [quarter*1024,+1024),
// 4 sub-chunks of 256 n staged transposed into LDS (ekT/vT [32][256] bf16 swizzled).
// Wave w covers n-slice w*64..+64 of each sub-chunk -> partial index quarter*4+w (16 total).
__global__ __launch_bounds__(256, 4) void k_ctx(const unsigned short* __restrict__ ekh,
                                                const unsigned short* __restrict__ vvh,
                                                float* __restrict__ pctx,
                                                float* __restrict__ pse) {
  extern __shared__ char lds[];                // ekT @0 (16KB), vT @16384 (16KB)

  const int tid = threadIdx.x;
  const int h = blockIdx.x & 3, quarter = blockIdx.x >> 2, b = blockIdx.y;
  const int wave = tid >> 6, lane = tid & 63, g = lane >> 4, c = lane & 15;
  const long nbase = (long)b * 4096 + quarter * 1024;

  f32x4 acc[2][2];
#pragma unroll
  for (int dt = 0; dt < 2; dt++) { acc[dt][0] = (f32x4){0.f,0.f,0.f,0.f}; acc[dt][1] = (f32x4){0.f,0.f,0.f,0.f}; }
  float se[2] = {0.f, 0.f};

  for (int sci = 0; sci < 4; sci++) {
    const long n0 = nbase + sci * 256;
    // issue global loads early (overlap previous MFMA phase)
    const uint4* esrc = (const uint4*)(ekh + ((long)h * 131072 + n0 + tid) * 32);
    const uint4* vsrc = (const uint4*)(vvh + ((long)h * 131072 + n0 + tid) * 32);
    uint4 ev[4], vq[4];
#pragma unroll
    for (int i = 0; i < 4; i++) { ev[i] = esrc[i]; vq[i] = vsrc[i]; }

    if (sci > 0) __syncthreads();              // prev MFMA reads done before overwrite

    // transposed LDS write: thread owns n = tid; writes 32 d's each for ek and v
#pragma unroll
    for (int i = 0; i < 4; i++) {
      u16x8 es = __builtin_bit_cast(u16x8, ev[i]);
      u16x8 vs = __builtin_bit_cast(u16x8, vq[i]);
#pragma unroll
      for (int j = 0; j < 8; j++) {
        int d = i * 8 + j;
        int ba = (d * 512 + tid * 2) ^ ((d & 7) << 4);
        *(unsigned short*)(lds + ba)         = es[j];
        *(unsigned short*)(lds + 16384 + ba) = vs[j];
      }
    }
    __syncthreads();

    // MFMA: wave's 64-n slice, 2 k-steps of 32
#pragma unroll
    for (int ks = 0; ks < 2; ks++) {
      const int noff = (wave * 64 + ks * 32 + g * 8) * 2;
      bf16x8 afr[2], bfr[2];
#pragma unroll
      for (int dt = 0; dt < 2; dt++) {
        int row = dt * 16 + c;
        afr[dt] = *(const bf16x8*)(lds + ((row * 512 + noff) ^ ((row & 7) << 4)));
      }
#pragma unroll
      for (int et = 0; et < 2; et++) {
        int row = et * 16 + c;
        bfr[et] = *(const bf16x8*)(lds + 16384 + ((row * 512 + noff) ^ ((row & 7) << 4)));
      }
#pragma unroll
      for (int dt = 0; dt < 2; dt++)
#pragma unroll
        for (int j = 0; j < 8; j++)
          se[dt] += bf2f((unsigned short)afr[dt][j]);
#pragma unroll
      for (int dt = 0; dt < 2; dt++)
#pragma unroll
        for (int et = 0; et < 2; et++)
          acc[dt][et] = __builtin_amdgcn_mfma_f32_16x16x32_bf16(afr[dt], bfr[et], acc[dt][et], 0, 0, 0);
    }
  }

  // write partials: index p = quarter*4 + wave  (16 per (b,h); k_ctxred unchanged)
  const int p = quarter * 4 + wave;
  const long pb = ((long)p * 128 + b * 4 + h) * 1024;
#pragma unroll
  for (int dt = 0; dt < 2; dt++)
#pragma unroll
    for (int et = 0; et < 2; et++)
#pragma unroll
      for (int r = 0; r < 4; r++)
        pctx[pb + (dt * 16 + g * 4 + r) * 32 + et * 16 + c] = acc[dt][et][r];

#pragma unroll
  for (int dt = 0; dt < 2; dt++) {
    se[dt] += __shfl_xor(se[dt], 16);
    se[dt] += __shfl_xor(se[dt], 32);
  }
  if (lane < 16) {
#pragma unroll
    for (int dt = 0; dt < 2; dt++)
      pse[((long)p * 128 + b * 4 + h) * 32 + dt * 16 + c] = se[dt];
  }
}

// ---------------- k_ctxred: reduce 16 partials, normalize, emit ctx bf16 ----------------
__global__ __launch_bounds__(256) void k_ctxred(const float* __restrict__ pctx,
                                                const float* __restrict__ pse,
                                                unsigned short* __restrict__ ctxg) {
  int idx = blockIdx.x * 256 + threadIdx.x;   // 131072 = 32*4*32*32
  int de = idx & 1023, d = de >> 5, bh = idx >> 10;
  float s = 0.f, sume = 0.f;
#pragma unroll
  for (int ch = 0; ch < 16; ch++) {
    s    += pctx[(ch * 128 + bh) * 1024 + de];
    sume += pse[(ch * 128 + bh) * 32 + d];
  }
  ctxg[idx] = f2bf(s / (sume * 4096.0f));     // softmax-normalize + v's 1/N
}

// ---------------- k_out: attn = q_s*ctx ; y = attn@Wout + b ; LayerNorm ----------------
__global__ __launch_bounds__(512, 2) void k_out(const unsigned short* __restrict__ qs,
                                                const unsigned short* __restrict__ ctxg,
                                                const unsigned short* __restrict__ woT,
                                                const float* __restrict__ bout,
                                                const float* __restrict__ lnsc,
                                                float* __restrict__ out) {
  extern __shared__ char lds[];
  char* lds_wo = lds;                                       // 32768 B, swizzled [c][k]
  char* lds_at = lds + 32768;                               // 32768 B, swizzled [row][col]; f32 flush later
  unsigned short* lds_cx = (unsigned short*)(lds + 65536);  // [4][32 e][32 d] bf16, 8192 B
  float* lds_bias  = (float*)(lds + 73728);
  float* lds_scale = (float*)(lds + 74240);

  const int tid = threadIdx.x;
  const long rowbase = (long)blockIdx.x * 128;
  const int b = blockIdx.x >> 5;

  {  // stage Wout^T
    const int4* src = (const int4*)woT;
    int4* dst = (int4*)lds_wo;
#pragma unroll
    for (int i = 0; i < 4; i++) {
      int u = tid + i * 512;
      dst[u ^ ((u >> 4) & 7)] = src[u];
    }
  }
  {  // stage ctx [h][d][e] -> LDS transposed [h][e][d]
    const unsigned int* src = (const unsigned int*)(ctxg + (long)b * 4096);
#pragma unroll
    for (int i = 0; i < 4; i++) {
      int u = tid + i * 512;           // one uint = elems (j, j+1), j = 2u
      unsigned int w = src[u];
      int j = u * 2;
      int e = j & 31, d = (j >> 5) & 31, h = j >> 10;
      lds_cx[(h * 32 + e) * 32 + d]     = (unsigned short)(w & 0xffffu);
      lds_cx[(h * 32 + e + 1) * 32 + d] = (unsigned short)(w >> 16);
    }
  }
  if (tid < 128) { lds_bias[tid] = bout[tid]; lds_scale[tid] = lnsc[tid]; }
  __syncthreads();

  const int lane = tid & 63, g = lane >> 4, c = lane & 15;
  const int wave = tid >> 6;

  // GEMM1: attn[16 rows][128] ; A = q_s straight from global (L2), B = ctx from LDS
  f32x4 acc1[4][2];
#pragma unroll
  for (int h = 0; h < 4; h++) { acc1[h][0] = (f32x4){0.f,0.f,0.f,0.f}; acc1[h][1] = (f32x4){0.f,0.f,0.f,0.f}; }
  const unsigned short* qrow = qs + (rowbase + wave * 16 + c) * 128;
#pragma unroll
  for (int h = 0; h < 4; h++) {
    bf16x8 a = *(const bf16x8*)(qrow + h * 32 + g * 8);
#pragma unroll
    for (int et = 0; et < 2; et++) {
      bf16x8 bq = *(const bf16x8*)(lds_cx + (h * 32 + et * 16 + c) * 32 + g * 8);
      acc1[h][et] = __builtin_amdgcn_mfma_f32_16x16x32_bf16(a, bq, acc1[h][et], 0, 0, 0);
    }
  }
  {  // attn -> LDS (bf16, swizzled) for the A-fragment round trip
    int rowl = wave * 16 + g * 4;
#pragma unroll
    for (int h = 0; h < 4; h++)
#pragma unroll
      for (int et = 0; et < 2; et++) {
        int col = (2 * h + et) * 16 + c;
#pragma unroll
        for (int r = 0; r < 4; r++) {
          int row = rowl + r;
          int ba = (row * 256 + col * 2) ^ ((row & 7) << 4);
          *(unsigned short*)(lds_at + ba) = f2bf(acc1[h][et][r]);
        }
      }
  }
  __syncthreads();

  // GEMM2: y = attn @ Wout
  f32x4 acc2[8];
#pragma unroll
  for (int ct = 0; ct < 8; ct++) acc2[ct] = (f32x4){0.f,0.f,0.f,0.f};
#pragma unroll
  for (int kk = 0; kk < 4; kk++) {
    int koff = (kk * 32 + g * 8) * 2;
    int arow = wave * 16 + c;
    bf16x8 a = *(const bf16x8*)(lds_at + ((arow * 256 + koff) ^ ((arow & 7) << 4)));
#pragma unroll
    for (int ct = 0; ct < 8; ct++) {
      int wrow = ct * 16 + c;
      bf16x8 bw = *(const bf16x8*)(lds_wo + ((wrow * 256 + koff) ^ ((wrow & 7) << 4)));
      acc2[ct] = __builtin_amdgcn_mfma_f32_16x16x32_bf16(a, bw, acc2[ct], 0, 0, 0);
    }
  }

  // bias + LayerNorm (per-row over 128 channels, shuffle reduction) -> keep in regs
  float biasv[8], scalev[8];
#pragma unroll
  for (int ct = 0; ct < 8; ct++) { biasv[ct] = lds_bias[ct * 16 + c]; scalev[ct] = lds_scale[ct * 16 + c]; }
#pragma unroll
  for (int ct = 0; ct < 8; ct++)
#pragma unroll
    for (int r = 0; r < 4; r++)
      acc2[ct][r] += biasv[ct];

#pragma unroll
  for (int r = 0; r < 4; r++) {
    float s = 0.f, ss = 0.f;
#pragma unroll
    for (int ct = 0; ct < 8; ct++) { float v = acc2[ct][r]; s += v; ss += v * v; }
    s  += __shfl_xor(s, 1);  s  += __shfl_xor(s, 2);  s  += __shfl_xor(s, 4);  s  += __shfl_xor(s, 8);
    ss += __shfl_xor(ss, 1); ss += __shfl_xor(ss, 2); ss += __shfl_xor(ss, 4); ss += __shfl_xor(ss, 8);
    float mu = s * 0.0078125f;
    float var = ss * 0.0078125f - mu * mu;
    float rstd = rsqrtf(var + 1e-5f);
#pragma unroll
    for (int ct = 0; ct < 8; ct++)
      acc2[ct][r] = (acc2[ct][r] - mu) * rstd * scalev[ct];
  }

  // coalesced store via lds_at (f32), two 64-row half-passes of 32KB each
#pragma unroll
  for (int half = 0; half < 2; half++) {
    __syncthreads();                     // lds_at free (after GEMM2 / previous flush)
    if ((wave >> 2) == half) {
      int rl0 = (wave & 3) * 16 + g * 4; // local row within half (0..63)
#pragma unroll
      for (int ct = 0; ct < 8; ct++)
#pragma unroll
        for (int r = 0; r < 4; r++) {
          int rl = rl0 + r;
          *(float*)(lds_at + ((rl * 512 + (ct * 16 + c) * 4) ^ ((rl & 7) << 4))) = acc2[ct][r];
        }
    }
    __syncthreads();
    {
      const long base = (rowbase + half * 64) * 32;   // int4 units (32 per 128-f32 row)
#pragma unroll
      for (int i = 0; i < 4; i++) {
        int u = tid + i * 512;
        int row = u >> 5;
        int4 v = *(const int4*)(lds_at + ((u * 16) ^ ((row & 7) << 4)));
        ((int4*)out)[base + u] = v;
      }
    }
  }
}

// ---------------- host ----------------
extern "C" void kernel_launch(void* const* d_in, const int* in_sizes, int n_in,
                              void* d_out, int out_size, void* d_ws, size_t ws_size,
                              hipStream_t stream) {
  (void)in_sizes; (void)n_in; (void)out_size; (void)ws_size;
  const float* x     = (const float*)d_in[0];
  const float* wqkv  = (const float*)d_in[1];
  const float* wout  = (const float*)d_in[2];
  const float* bo    = (const float*)d_in[3];
  const float* lnsc  = (const float*)d_in[4];
  float* out = (float*)d_out;

  char* ws = (char*)d_ws;
  unsigned short* qs   = (unsigned short*)(ws + OFF_QS);
  unsigned short* ekh  = (unsigned short*)(ws + OFF_EK);
  unsigned short* vvh  = (unsigned short*)(ws + OFF_VV);
  float*          pctx = (float*)(ws + OFF_PCTX);
  float*          pse  = (float*)(ws + OFF_PSE);
  unsigned short* ctxg = (unsigned short*)(ws + OFF_CTXG);
  unsigned short* wqT  = (unsigned short*)(ws + OFF_WQT);
  unsigned short* woT  = (unsigned short*)(ws + OFF_WOT);

  k_prep<<<dim3(256), dim3(256), 0, stream>>>(wqkv, wout, wqT, woT);
  k_qkv<<<dim3(1024, 3), dim3(512), 65536, stream>>>(x, wqT, qs, ekh, vvh);
  k_ctx<<<dim3(16, 32), dim3(256), 32768, stream>>>(ekh, vvh, pctx, pse);
  k_ctxred<<<dim3(512), dim3(256), 0, stream>>>(pctx, pse, ctxg);
  k_out<<<dim3(1024), dim3(512), 74752, stream>>>(qs, ctxg, woT, bo, lnsc, out);
}